// Round 5
// baseline (1286.239 us; speedup 1.0000x reference)
//
#include <hip/hip_runtime.h>

#define NN  8000
#define EE  200000
#define BB  4
#define VV  20
#define NVV 8000
#define NRR 200
#define HH  128
#define OO  64
#define LL  3

// ---------------- small zero ----------------
__global__ void k_zero_small(float* p, int n) {
  int i = blockIdx.x * 256 + threadIdx.x;
  if (i < n) p[i] = 0.f;
}

// ---------------- node projection + per-layer alpha dots ----------------
// x[i,h] = node_emb[node_ids[i]] @ lin_w + lin_b ; snode[l,i] = x[i,:]·alpha_w[l]
__global__ __launch_bounds__(128) void k_proj_nodes(
    const int* __restrict__ node_ids, const float* __restrict__ emb,
    const float* __restrict__ lin_w, const float* __restrict__ lin_b,
    const float* __restrict__ alpha_w, float* __restrict__ x,
    float* __restrict__ snode)
{
  int i = blockIdx.x, t = threadIdx.x;
  __shared__ float row[HH];
  __shared__ float red[HH];
  row[t] = emb[node_ids[i] * HH + t];
  __syncthreads();
  float acc = lin_b[t];
  #pragma unroll 4
  for (int d = 0; d < HH; ++d) acc += row[d] * lin_w[d * HH + t];
  x[i * HH + t] = acc;
  for (int l = 0; l < LL; ++l) {
    red[t] = acc * alpha_w[l * HH + t];
    __syncthreads();
    for (int s = 64; s > 0; s >>= 1) {
      if (t < s) red[t] += red[t + s];
      __syncthreads();
    }
    if (t == 0) snode[l * NN + i] = red[0];
    __syncthreads();
  }
}

// ---------------- relation projection + per-layer wr dots ----------------
__global__ __launch_bounds__(128) void k_proj_rels(
    const float* __restrict__ rel_emb, const float* __restrict__ lin_w,
    const float* __restrict__ lin_b, const float* __restrict__ wr_w,
    const float* __restrict__ wr_b, float* __restrict__ relp,
    float* __restrict__ reldot)
{
  int r = blockIdx.x, t = threadIdx.x;
  __shared__ float row[HH];
  __shared__ float red[HH];
  row[t] = rel_emb[r * HH + t];
  __syncthreads();
  float acc = lin_b[t];
  #pragma unroll 4
  for (int d = 0; d < HH; ++d) acc += row[d] * lin_w[d * HH + t];
  relp[r * HH + t] = acc;
  for (int l = 0; l < LL; ++l) {
    red[t] = acc * wr_w[l * HH + t];
    __syncthreads();
    for (int s = 64; s > 0; s >>= 1) {
      if (t < s) red[t] += red[t + s];
      __syncthreads();
    }
    if (t == 0) reldot[l * NRR + r] = red[0] + wr_b[l];
    __syncthreads();
  }
}

// ---------------- beta0[l,b] = tanh(visit_node[b,0,:]·beta_w[l] + beta_b[l]) * exp(DECAY*V) ----------------
__global__ __launch_bounds__(256) void k_beta(
    const float* __restrict__ visit_node, const float* __restrict__ beta_w,
    const float* __restrict__ beta_b, float* __restrict__ beta0)
{
  int l = blockIdx.x >> 2, b = blockIdx.x & 3, t = threadIdx.x;
  __shared__ float red[256];
  float acc = 0.f;
  for (int n = t; n < NVV; n += 256)
    acc += visit_node[(b * VV + 0) * NVV + n] * beta_w[l * NVV + n];
  red[t] = acc;
  __syncthreads();
  for (int s = 128; s > 0; s >>= 1) {
    if (t < s) red[t] += red[t + s];
    __syncthreads();
  }
  if (t == 0) beta0[l * BB + b] = tanhf(red[0] + beta_b[l]) * expf(0.03f * 20.0f);
}

// ---------------- attn0[l,b,n] = softmax_v(vn*s+ab)[v=0] * beta0[l,b] ----------------
__global__ __launch_bounds__(256) void k_attn(
    const float* __restrict__ visit_node, const float* __restrict__ snode,
    const float* __restrict__ alpha_b, const float* __restrict__ beta0,
    float* __restrict__ attn0)
{
  int idx = blockIdx.x * 256 + threadIdx.x;
  if (idx >= BB * NVV) return;
  int b = idx / NVV, n = idx % NVV;
  float vn[VV];
  #pragma unroll
  for (int v = 0; v < VV; ++v) vn[v] = visit_node[(b * VV + v) * NVV + n];
  for (int l = 0; l < LL; ++l) {
    float s = (n < NN / BB) ? snode[l * NN + b * (NN / BB) + n] : 0.0f;
    float ab = alpha_b[l];
    float m = -1e30f;
    #pragma unroll
    for (int v = 0; v < VV; ++v) m = fmaxf(m, vn[v] * s + ab);
    float sum = 0.f;
    #pragma unroll
    for (int v = 0; v < VV; ++v) sum += expf(vn[v] * s + ab - m);
    float a0 = expf(vn[0] * s + ab - m) / sum;
    attn0[(l * BB + b) * NVV + n] = a0 * beta0[l * BB + b];
  }
}

// ---------------- edge scatter: agg[dst] += relu(x[src]*a + w*relp[rid]) ----------------
// one thread per (edge, 4 features): float4 loads, 4 atomics
__global__ __launch_bounds__(256) void k_edges(
    const int* __restrict__ edge_index, const int* __restrict__ rel_ids,
    const int* __restrict__ node_ids, const int* __restrict__ batch,
    const float* __restrict__ x, const float* __restrict__ relp,
    const float* __restrict__ attn0, const float* __restrict__ reldot,
    float* __restrict__ agg, int l)
{
  int idx = blockIdx.x * 256 + threadIdx.x;
  if (idx >= EE * (HH / 4)) return;
  int e = idx >> 5;             // HH/4 = 32 threads per edge
  int h4 = (idx & 31) << 2;     // feature offset 0,4,...,124
  int src = edge_index[e];
  int dst = edge_index[EE + e];
  int rid = rel_ids[e];
  float a = attn0[(l * BB + batch[src]) * NVV + node_ids[src]];
  float w = reldot[l * NRR + rid];
  const float4 xs = *(const float4*)&x[src * HH + h4];
  const float4 rp = *(const float4*)&relp[rid * HH + h4];
  float* dp = &agg[dst * HH + h4];
  atomicAdd(dp + 0, fmaxf(xs.x * a + w * rp.x, 0.f));
  atomicAdd(dp + 1, fmaxf(xs.y * a + w * rp.y, 0.f));
  atomicAdd(dp + 2, fmaxf(xs.z * a + w * rp.z, 0.f));
  atomicAdd(dp + 3, fmaxf(xs.w * a + w * rp.w, 0.f));
}

// ---------------- conv: x[i] = relu(agg[i] @ conv_w[l] + conv_b[l]) ----------------
__global__ __launch_bounds__(128) void k_conv(
    const float* __restrict__ agg, const float* __restrict__ conv_w,
    const float* __restrict__ conv_b, float* __restrict__ x, int l)
{
  int i = blockIdx.x, t = threadIdx.x;
  __shared__ float row[HH];
  row[t] = agg[i * HH + t];
  __syncthreads();
  float acc = conv_b[l * HH + t];
  #pragma unroll 4
  for (int d = 0; d < HH; ++d) acc += row[d] * conv_w[(l * HH + d) * HH + t];
  x[i * HH + t] = fmaxf(acc, 0.f);
}

// ---------------- x_graph partial sums (chunked, atomic) ----------------
__global__ __launch_bounds__(128) void k_xgraph(
    const float* __restrict__ x, float* __restrict__ xg_raw)
{
  int b = blockIdx.x >> 4, c = blockIdx.x & 15, t = threadIdx.x;
  const int per = (NN / BB) / 16;  // 125 nodes per chunk
  int base = b * (NN / BB) + c * per;
  float acc = 0.f;
  for (int i = 0; i < per; ++i) acc += x[(base + i) * HH + t];
  atomicAdd(&xg_raw[b * HH + t], acc);
}

// ---------------- x_node raw partial sums + denom (chunked, atomic) ----------------
__global__ __launch_bounds__(128) void k_xnode(
    const float* __restrict__ ehr, const float* __restrict__ emb,
    float* __restrict__ xn_raw, float* __restrict__ denom)
{
  int b = blockIdx.x >> 5, c = blockIdx.x & 31, t = threadIdx.x;
  const int per = NVV / 32;  // 250
  int base = c * per;
  float acc = 0.f;
  for (int n = base; n < base + per; ++n)
    acc += ehr[b * NVV + n] * emb[n * HH + t];
  atomicAdd(&xn_raw[b * HH + t], acc);
  // denom partial
  __shared__ float red[128];
  float dsum = 0.f;
  for (int n = base + t; n < base + per; n += 128) dsum += ehr[b * NVV + n];
  red[t] = dsum;
  __syncthreads();
  for (int s = 64; s > 0; s >>= 1) {
    if (t < s) red[t] += red[t + s];
    __syncthreads();
  }
  if (t == 0) atomicAdd(&denom[b], red[0]);
}

// ---------------- final: project x_node, concat, MLP ----------------
__global__ __launch_bounds__(128) void k_final(
    const float* __restrict__ xg_raw, const float* __restrict__ xn_raw,
    const float* __restrict__ denom, const float* __restrict__ lin_w,
    const float* __restrict__ lin_b, const float* __restrict__ mlp_w,
    const float* __restrict__ mlp_b, float* __restrict__ out)
{
  int b = blockIdx.x, t = threadIdx.x;
  __shared__ float xg[HH], xn[HH], xnp[HH];
  xg[t] = xg_raw[b * HH + t] * (1.0f / (NN / BB));
  xn[t] = xn_raw[b * HH + t] / denom[b];
  __syncthreads();
  float a3 = lin_b[t];
  #pragma unroll 4
  for (int d = 0; d < HH; ++d) a3 += xn[d] * lin_w[d * HH + t];
  xnp[t] = a3;
  __syncthreads();
  if (t < OO) {
    float a4 = mlp_b[t];
    #pragma unroll 4
    for (int h = 0; h < HH; ++h)
      a4 += xg[h] * mlp_w[h * OO + t] + xnp[h] * mlp_w[(HH + h) * OO + t];
    out[b * OO + t] = a4;
  }
}

extern "C" void kernel_launch(void* const* d_in, const int* in_sizes, int n_in,
                              void* d_out, int out_size, void* d_ws, size_t ws_size,
                              hipStream_t stream) {
  const int*   node_ids   = (const int*)d_in[0];
  const int*   rel_ids    = (const int*)d_in[1];
  const int*   edge_index = (const int*)d_in[2];
  const int*   batch      = (const int*)d_in[3];
  const float* visit_node = (const float*)d_in[4];
  const float* ehr        = (const float*)d_in[5];
  const float* node_emb   = (const float*)d_in[6];
  const float* rel_emb    = (const float*)d_in[7];
  const float* lin_w      = (const float*)d_in[8];
  const float* lin_b      = (const float*)d_in[9];
  const float* alpha_w    = (const float*)d_in[10];
  const float* alpha_b    = (const float*)d_in[11];
  const float* beta_w     = (const float*)d_in[12];
  const float* beta_b     = (const float*)d_in[13];
  const float* conv_w     = (const float*)d_in[14];
  const float* conv_b     = (const float*)d_in[15];
  const float* wr_w       = (const float*)d_in[16];
  const float* wr_b       = (const float*)d_in[17];
  const float* mlp_w      = (const float*)d_in[18];
  const float* mlp_b      = (const float*)d_in[19];
  float* out = (float*)d_out;

  float* ws = (float*)d_ws;
  float* x      = ws; ws += NN * HH;
  float* agg    = ws; ws += NN * HH;
  float* relp   = ws; ws += NRR * HH;
  float* reldot = ws; ws += LL * NRR;
  float* snode  = ws; ws += LL * NN;
  float* beta0  = ws; ws += LL * BB;
  float* attn0  = ws; ws += LL * BB * NVV;
  float* xg_raw = ws; ws += BB * HH;
  float* xn_raw = ws; ws += BB * HH;
  float* denom  = ws; ws += BB;

  // zero the small accumulator region (xg_raw, xn_raw, denom are contiguous)
  int nsmall = BB * HH * 2 + BB;
  hipLaunchKernelGGL(k_zero_small, dim3((nsmall + 255) / 256), dim3(256), 0, stream,
                     xg_raw, nsmall);

  hipLaunchKernelGGL(k_proj_nodes, dim3(NN), dim3(HH), 0, stream,
                     node_ids, node_emb, lin_w, lin_b, alpha_w, x, snode);
  hipLaunchKernelGGL(k_proj_rels, dim3(NRR), dim3(HH), 0, stream,
                     rel_emb, lin_w, lin_b, wr_w, wr_b, relp, reldot);
  hipLaunchKernelGGL(k_beta, dim3(LL * BB), dim3(256), 0, stream,
                     visit_node, beta_w, beta_b, beta0);
  hipLaunchKernelGGL(k_attn, dim3((BB * NVV + 255) / 256), dim3(256), 0, stream,
                     visit_node, snode, alpha_b, beta0, attn0);

  for (int l = 0; l < LL; ++l) {
    // agg = x  (so conv computes (sum(msg)+x) @ W)
    hipMemcpyAsync(agg, x, (size_t)NN * HH * sizeof(float),
                   hipMemcpyDeviceToDevice, stream);
    hipLaunchKernelGGL(k_edges, dim3((EE * (HH / 4)) / 256), dim3(256), 0, stream,
                       edge_index, rel_ids, node_ids, batch, x, relp, attn0,
                       reldot, agg, l);
    hipLaunchKernelGGL(k_conv, dim3(NN), dim3(HH), 0, stream,
                       agg, conv_w, conv_b, x, l);
  }

  hipLaunchKernelGGL(k_xgraph, dim3(BB * 16), dim3(HH), 0, stream, x, xg_raw);
  hipLaunchKernelGGL(k_xnode, dim3(BB * 32), dim3(HH), 0, stream,
                     ehr, node_emb, xn_raw, denom);
  hipLaunchKernelGGL(k_final, dim3(BB), dim3(HH), 0, stream,
                     xg_raw, xn_raw, denom, lin_w, lin_b, mlp_w, mlp_b, out);
}

// Round 8
// 358.928 us; speedup vs baseline: 3.5836x; 3.5836x over previous
//
#include <hip/hip_runtime.h>

#define NN  8000
#define EE  200000
#define BB  4
#define VV  20
#define NVV 8000
#define NRR 200
#define HH  128
#define OO  64
#define LL  3

// ---------------- zero helpers ----------------
__global__ void k_zero_small(float* p, int n) {
  int i = blockIdx.x * 256 + threadIdx.x;
  if (i < n) p[i] = 0.f;
}
__global__ void k_zero_int(int* p, int n) {
  int i = blockIdx.x * 256 + threadIdx.x;
  if (i < n) p[i] = 0;
}

// ---------------- node projection + per-layer alpha dots (shuffle reduce) ----------------
// x[i,h] = node_emb[node_ids[i]] @ lin_w + lin_b ; snode[l,i] = x[i,:]·alpha_w[l]
__global__ __launch_bounds__(128) void k_proj_nodes(
    const int* __restrict__ node_ids, const float* __restrict__ emb,
    const float* __restrict__ lin_w, const float* __restrict__ lin_b,
    const float* __restrict__ alpha_w, float* __restrict__ x,
    float* __restrict__ snode)
{
  int i = blockIdx.x, t = threadIdx.x;
  __shared__ float row[HH];
  __shared__ float part[LL][2];
  row[t] = emb[node_ids[i] * HH + t];
  __syncthreads();
  float acc = lin_b[t];
  #pragma unroll 4
  for (int d = 0; d < HH; ++d) acc += row[d] * lin_w[d * HH + t];
  x[i * HH + t] = acc;
  #pragma unroll
  for (int l = 0; l < LL; ++l) {
    float v = acc * alpha_w[l * HH + t];
    for (int off = 32; off > 0; off >>= 1) v += __shfl_down(v, off, 64);
    if ((t & 63) == 0) part[l][t >> 6] = v;
  }
  __syncthreads();
  if (t == 0) {
    #pragma unroll
    for (int l = 0; l < LL; ++l) snode[l * NN + i] = part[l][0] + part[l][1];
  }
}

// ---------------- relation projection + per-layer wr dots ----------------
__global__ __launch_bounds__(128) void k_proj_rels(
    const float* __restrict__ rel_emb, const float* __restrict__ lin_w,
    const float* __restrict__ lin_b, const float* __restrict__ wr_w,
    const float* __restrict__ wr_b, float* __restrict__ relp,
    float* __restrict__ reldot)
{
  int r = blockIdx.x, t = threadIdx.x;
  __shared__ float row[HH];
  __shared__ float part[LL][2];
  row[t] = rel_emb[r * HH + t];
  __syncthreads();
  float acc = lin_b[t];
  #pragma unroll 4
  for (int d = 0; d < HH; ++d) acc += row[d] * lin_w[d * HH + t];
  relp[r * HH + t] = acc;
  #pragma unroll
  for (int l = 0; l < LL; ++l) {
    float v = acc * wr_w[l * HH + t];
    for (int off = 32; off > 0; off >>= 1) v += __shfl_down(v, off, 64);
    if ((t & 63) == 0) part[l][t >> 6] = v;
  }
  __syncthreads();
  if (t == 0) {
    #pragma unroll
    for (int l = 0; l < LL; ++l) reldot[l * NRR + r] = part[l][0] + part[l][1] + wr_b[l];
  }
}

// ---------------- beta0[l,b] = tanh(visit_node[b,0,:]·beta_w[l] + beta_b[l]) * exp(DECAY*V) ----------------
__global__ __launch_bounds__(256) void k_beta(
    const float* __restrict__ visit_node, const float* __restrict__ beta_w,
    const float* __restrict__ beta_b, float* __restrict__ beta0)
{
  int l = blockIdx.x >> 2, b = blockIdx.x & 3, t = threadIdx.x;
  __shared__ float red[256];
  float acc = 0.f;
  for (int n = t; n < NVV; n += 256)
    acc += visit_node[(b * VV + 0) * NVV + n] * beta_w[l * NVV + n];
  red[t] = acc;
  __syncthreads();
  for (int s = 128; s > 0; s >>= 1) {
    if (t < s) red[t] += red[t + s];
    __syncthreads();
  }
  if (t == 0) beta0[l * BB + b] = tanhf(red[0] + beta_b[l]) * expf(0.03f * 20.0f);
}

// ---------------- attn0[l,b,n] = softmax_v(vn*s+ab)[v=0] * beta0[l,b] ----------------
__global__ __launch_bounds__(256) void k_attn(
    const float* __restrict__ visit_node, const float* __restrict__ snode,
    const float* __restrict__ alpha_b, const float* __restrict__ beta0,
    float* __restrict__ attn0)
{
  int idx = blockIdx.x * 256 + threadIdx.x;
  if (idx >= BB * NVV) return;
  int b = idx / NVV, n = idx % NVV;
  float vn[VV];
  #pragma unroll
  for (int v = 0; v < VV; ++v) vn[v] = visit_node[(b * VV + v) * NVV + n];
  for (int l = 0; l < LL; ++l) {
    float s = (n < NN / BB) ? snode[l * NN + b * (NN / BB) + n] : 0.0f;
    float ab = alpha_b[l];
    float m = -1e30f;
    #pragma unroll
    for (int v = 0; v < VV; ++v) m = fmaxf(m, vn[v] * s + ab);
    float sum = 0.f;
    #pragma unroll
    for (int v = 0; v < VV; ++v) sum += expf(vn[v] * s + ab - m);
    float a0 = expf(vn[0] * s + ab - m) / sum;
    attn0[(l * BB + b) * NVV + n] = a0 * beta0[l * BB + b];
  }
}

// ---------------- anode[l,i] = attn0[l, batch[i], node_ids[i]] ----------------
__global__ void k_anode(const int* __restrict__ node_ids, const int* __restrict__ batch,
                        const float* __restrict__ attn0, float* __restrict__ anode)
{
  int i = blockIdx.x * 256 + threadIdx.x;
  if (i >= NN) return;
  int b = batch[i], nid = node_ids[i];
  #pragma unroll
  for (int l = 0; l < LL; ++l) anode[l * NN + i] = attn0[(l * BB + b) * NVV + nid];
}

// ---------------- CSR build: histogram, scan, scatter ----------------
__global__ void k_hist(const int* __restrict__ edge_index, int* __restrict__ deg) {
  int e = blockIdx.x * 256 + threadIdx.x;
  if (e >= EE) return;
  atomicAdd(&deg[edge_index[EE + e]], 1);
}

__global__ __launch_bounds__(1024) void k_scan(const int* __restrict__ deg,
                                               int* __restrict__ row_ptr)
{
  int t = threadIdx.x;
  __shared__ int ps[1024];
  int local[8];
  int base = t * 8;
  int s = 0;
  #pragma unroll
  for (int j = 0; j < 8; ++j) {
    int idx = base + j;
    int v = (idx < NN) ? deg[idx] : 0;
    local[j] = s; s += v;
  }
  ps[t] = s;
  __syncthreads();
  for (int off = 1; off < 1024; off <<= 1) {
    int v = (t >= off) ? ps[t - off] : 0;
    __syncthreads();
    ps[t] += v;
    __syncthreads();
  }
  int excl = (t == 0) ? 0 : ps[t - 1];
  #pragma unroll
  for (int j = 0; j < 8; ++j) {
    int idx = base + j;
    if (idx < NN) row_ptr[idx] = excl + local[j];
  }
  if (t == 1023) row_ptr[NN] = ps[1023];
}

__global__ void k_scatter(const int* __restrict__ edge_index, const int* __restrict__ rel_ids,
                          const int* __restrict__ row_ptr, int* __restrict__ cursor,
                          int* __restrict__ csr_src, int* __restrict__ csr_rid)
{
  int e = blockIdx.x * 256 + threadIdx.x;
  if (e >= EE) return;
  int dst = edge_index[EE + e];
  int p = row_ptr[dst] + atomicAdd(&cursor[dst], 1);
  csr_src[p] = edge_index[e];
  csr_rid[p] = rel_ids[e];
}

// ---------------- fused gather + conv ----------------
// agg_row = xin[i] + sum_{e: dst=i} relu(xin[src]*anode[src] + reldot[rid]*relp[rid])
// xout[i] = relu(agg_row @ conv_w[l] + conv_b[l])
__global__ __launch_bounds__(128) void k_gather_conv(
    const int* __restrict__ row_ptr, const int* __restrict__ csr_src,
    const int* __restrict__ csr_rid, const float* __restrict__ xin,
    const float* __restrict__ relp, const float* __restrict__ anode,
    const float* __restrict__ reldot, const float* __restrict__ conv_w,
    const float* __restrict__ conv_b, float* __restrict__ xout, int l)
{
  int i = blockIdx.x, t = threadIdx.x;
  __shared__ float wl[NRR];
  __shared__ float aggrow[HH];
  for (int r = t; r < NRR; r += HH) wl[r] = reldot[l * NRR + r];
  __syncthreads();
  float acc = xin[i * HH + t];
  int k0 = row_ptr[i], k1 = row_ptr[i + 1];
  for (int k = k0; k < k1; ++k) {
    int src = csr_src[k];
    int rid = csr_rid[k];
    float a = anode[l * NN + src];
    acc += fmaxf(xin[src * HH + t] * a + wl[rid] * relp[rid * HH + t], 0.f);
  }
  aggrow[t] = acc;
  __syncthreads();
  float o = conv_b[l * HH + t];
  #pragma unroll 4
  for (int d = 0; d < HH; ++d) o += aggrow[d] * conv_w[(l * HH + d) * HH + t];
  xout[i * HH + t] = fmaxf(o, 0.f);
}

// ---------------- x_graph partial sums (chunked, atomic) ----------------
__global__ __launch_bounds__(128) void k_xgraph(
    const float* __restrict__ x, float* __restrict__ xg_raw)
{
  int b = blockIdx.x >> 4, c = blockIdx.x & 15, t = threadIdx.x;
  const int per = (NN / BB) / 16;  // 125 nodes per chunk
  int base = b * (NN / BB) + c * per;
  float acc = 0.f;
  for (int i = 0; i < per; ++i) acc += x[(base + i) * HH + t];
  atomicAdd(&xg_raw[b * HH + t], acc);
}

// ---------------- x_node raw partial sums + denom (chunked, atomic) ----------------
__global__ __launch_bounds__(128) void k_xnode(
    const float* __restrict__ ehr, const float* __restrict__ emb,
    float* __restrict__ xn_raw, float* __restrict__ denom)
{
  int b = blockIdx.x >> 5, c = blockIdx.x & 31, t = threadIdx.x;
  const int per = NVV / 32;  // 250
  int base = c * per;
  float acc = 0.f;
  for (int n = base; n < base + per; ++n)
    acc += ehr[b * NVV + n] * emb[n * HH + t];
  atomicAdd(&xn_raw[b * HH + t], acc);
  // denom partial
  __shared__ float red[128];
  float dsum = 0.f;
  for (int n = base + t; n < base + per; n += 128) dsum += ehr[b * NVV + n];
  red[t] = dsum;
  __syncthreads();
  for (int s = 64; s > 0; s >>= 1) {
    if (t < s) red[t] += red[t + s];
    __syncthreads();
  }
  if (t == 0) atomicAdd(&denom[b], red[0]);
}

// ---------------- final: project x_node, concat, MLP ----------------
__global__ __launch_bounds__(128) void k_final(
    const float* __restrict__ xg_raw, const float* __restrict__ xn_raw,
    const float* __restrict__ denom, const float* __restrict__ lin_w,
    const float* __restrict__ lin_b, const float* __restrict__ mlp_w,
    const float* __restrict__ mlp_b, float* __restrict__ out)
{
  int b = blockIdx.x, t = threadIdx.x;
  __shared__ float xg[HH], xn[HH], xnp[HH];
  xg[t] = xg_raw[b * HH + t] * (1.0f / (NN / BB));
  xn[t] = xn_raw[b * HH + t] / denom[b];
  __syncthreads();
  float a3 = lin_b[t];
  #pragma unroll 4
  for (int d = 0; d < HH; ++d) a3 += xn[d] * lin_w[d * HH + t];
  xnp[t] = a3;
  __syncthreads();
  if (t < OO) {
    float a4 = mlp_b[t];
    #pragma unroll 4
    for (int h = 0; h < HH; ++h)
      a4 += xg[h] * mlp_w[h * OO + t] + xnp[h] * mlp_w[(HH + h) * OO + t];
    out[b * OO + t] = a4;
  }
}

extern "C" void kernel_launch(void* const* d_in, const int* in_sizes, int n_in,
                              void* d_out, int out_size, void* d_ws, size_t ws_size,
                              hipStream_t stream) {
  const int*   node_ids   = (const int*)d_in[0];
  const int*   rel_ids    = (const int*)d_in[1];
  const int*   edge_index = (const int*)d_in[2];
  const int*   batch      = (const int*)d_in[3];
  const float* visit_node = (const float*)d_in[4];
  const float* ehr        = (const float*)d_in[5];
  const float* node_emb   = (const float*)d_in[6];
  const float* rel_emb    = (const float*)d_in[7];
  const float* lin_w      = (const float*)d_in[8];
  const float* lin_b      = (const float*)d_in[9];
  const float* alpha_w    = (const float*)d_in[10];
  const float* alpha_b    = (const float*)d_in[11];
  const float* beta_w     = (const float*)d_in[12];
  const float* beta_b     = (const float*)d_in[13];
  const float* conv_w     = (const float*)d_in[14];
  const float* conv_b     = (const float*)d_in[15];
  const float* wr_w       = (const float*)d_in[16];
  const float* wr_b       = (const float*)d_in[17];
  const float* mlp_w      = (const float*)d_in[18];
  const float* mlp_b      = (const float*)d_in[19];
  float* out = (float*)d_out;

  float* ws = (float*)d_ws;
  float* xA     = ws; ws += NN * HH;
  float* xB     = ws; ws += NN * HH;
  float* relp   = ws; ws += NRR * HH;
  float* reldot = ws; ws += LL * NRR;
  float* snode  = ws; ws += LL * NN;
  float* beta0  = ws; ws += LL * BB;
  float* attn0  = ws; ws += LL * BB * NVV;
  float* anode  = ws; ws += LL * NN;
  float* xg_raw = ws; ws += BB * HH;
  float* xn_raw = ws; ws += BB * HH;
  float* denom  = ws; ws += BB;
  int* iws      = (int*)ws;
  int* deg      = iws; iws += NN;       // deg and cursor contiguous (zeroed together)
  int* cursor   = iws; iws += NN;
  int* row_ptr  = iws; iws += NN + 1;
  int* csr_src  = iws; iws += EE;
  int* csr_rid  = iws; iws += EE;

  // zero accumulators + CSR counters
  int nsmall = BB * HH * 2 + BB;
  hipLaunchKernelGGL(k_zero_small, dim3((nsmall + 255) / 256), dim3(256), 0, stream,
                     xg_raw, nsmall);
  hipLaunchKernelGGL(k_zero_int, dim3((2 * NN + 255) / 256), dim3(256), 0, stream,
                     deg, 2 * NN);

  // projections + attention scalars
  hipLaunchKernelGGL(k_proj_nodes, dim3(NN), dim3(HH), 0, stream,
                     node_ids, node_emb, lin_w, lin_b, alpha_w, xA, snode);
  hipLaunchKernelGGL(k_proj_rels, dim3(NRR), dim3(HH), 0, stream,
                     rel_emb, lin_w, lin_b, wr_w, wr_b, relp, reldot);
  hipLaunchKernelGGL(k_beta, dim3(LL * BB), dim3(256), 0, stream,
                     visit_node, beta_w, beta_b, beta0);
  hipLaunchKernelGGL(k_attn, dim3((BB * NVV + 255) / 256), dim3(256), 0, stream,
                     visit_node, snode, alpha_b, beta0, attn0);
  hipLaunchKernelGGL(k_anode, dim3((NN + 255) / 256), dim3(256), 0, stream,
                     node_ids, batch, attn0, anode);

  // CSR build (by dst)
  hipLaunchKernelGGL(k_hist, dim3((EE + 255) / 256), dim3(256), 0, stream,
                     edge_index, deg);
  hipLaunchKernelGGL(k_scan, dim3(1), dim3(1024), 0, stream, deg, row_ptr);
  hipLaunchKernelGGL(k_scatter, dim3((EE + 255) / 256), dim3(256), 0, stream,
                     edge_index, rel_ids, row_ptr, cursor, csr_src, csr_rid);

  // layers: fused gather + conv, ping-pong buffers
  const float* xin = xA;
  float* xout = xB;
  for (int l = 0; l < LL; ++l) {
    hipLaunchKernelGGL(k_gather_conv, dim3(NN), dim3(HH), 0, stream,
                       row_ptr, csr_src, csr_rid, xin, relp, anode, reldot,
                       conv_w, conv_b, xout, l);
    const float* tmp = xin; xin = xout; xout = (float*)tmp;
  }
  // after 3 layers, final x is in xB (A->B, B->A, A->B)

  hipLaunchKernelGGL(k_xgraph, dim3(BB * 16), dim3(HH), 0, stream, xB, xg_raw);
  hipLaunchKernelGGL(k_xnode, dim3(BB * 32), dim3(HH), 0, stream,
                     ehr, node_emb, xn_raw, denom);
  hipLaunchKernelGGL(k_final, dim3(BB), dim3(HH), 0, stream,
                     xg_raw, xn_raw, denom, lin_w, lin_b, mlp_w, mlp_b, out);
}

// Round 11
// 320.700 us; speedup vs baseline: 4.0107x; 1.1192x over previous
//
#include <hip/hip_runtime.h>

#define NN  8000
#define EE  200000
#define BB  4
#define VV  20
#define NVV 8000
#define NRR 200
#define HH  128
#define OO  64
#define LL  3
#define NPB 8   // nodes per block (proj + gather)

// ---------------- fused zero: float accum region + int region ----------------
__global__ void k_zero(float* fz, int nf, int* iz, int ni) {
  int i = blockIdx.x * 256 + threadIdx.x;
  if (i < nf) fz[i] = 0.f;
  if (i < ni) iz[i] = 0;
}

// ---------------- node projection, 8 nodes/block + per-layer alpha dots ----------------
__global__ __launch_bounds__(128) void k_proj_nodes(
    const int* __restrict__ node_ids, const float* __restrict__ emb,
    const float* __restrict__ lin_w, const float* __restrict__ lin_b,
    const float* __restrict__ alpha_w, float* __restrict__ x,
    float* __restrict__ snode)
{
  int blk = blockIdx.x, t = threadIdx.x;
  __shared__ float er[NPB][HH];
  __shared__ float part[LL][NPB][2];
  int base = blk * NPB;
  #pragma unroll
  for (int n = 0; n < NPB; ++n)
    er[n][t] = emb[node_ids[base + n] * HH + t];
  __syncthreads();
  float bt = lin_b[t];
  float acc[NPB];
  #pragma unroll
  for (int n = 0; n < NPB; ++n) acc[n] = bt;
  for (int d4 = 0; d4 < HH / 4; ++d4) {
    float e4[NPB][4];
    #pragma unroll
    for (int n = 0; n < NPB; ++n) {
      float4 v = *(const float4*)&er[n][d4 * 4];
      e4[n][0] = v.x; e4[n][1] = v.y; e4[n][2] = v.z; e4[n][3] = v.w;
    }
    #pragma unroll
    for (int j = 0; j < 4; ++j) {
      float lwv = lin_w[(d4 * 4 + j) * HH + t];
      #pragma unroll
      for (int n = 0; n < NPB; ++n) acc[n] += e4[n][j] * lwv;
    }
  }
  #pragma unroll
  for (int n = 0; n < NPB; ++n) x[(base + n) * HH + t] = acc[n];
  #pragma unroll
  for (int l = 0; l < LL; ++l) {
    float aw = alpha_w[l * HH + t];
    #pragma unroll
    for (int n = 0; n < NPB; ++n) {
      float v = acc[n] * aw;
      for (int off = 32; off > 0; off >>= 1) v += __shfl_down(v, off, 64);
      if ((t & 63) == 0) part[l][n][t >> 6] = v;
    }
  }
  __syncthreads();
  if (t < LL * NPB) {
    int l = t / NPB, n = t % NPB;
    snode[l * NN + base + n] = part[l][n][0] + part[l][n][1];
  }
}

// ---------------- relation projection + fused wrelp = reldot * relp ----------------
__global__ __launch_bounds__(128) void k_proj_rels(
    const float* __restrict__ rel_emb, const float* __restrict__ lin_w,
    const float* __restrict__ lin_b, const float* __restrict__ wr_w,
    const float* __restrict__ wr_b, float* __restrict__ wrelp)
{
  int r = blockIdx.x, t = threadIdx.x;
  __shared__ float row[HH];
  __shared__ float part[LL][2];
  row[t] = rel_emb[r * HH + t];
  __syncthreads();
  float acc = lin_b[t];
  #pragma unroll 4
  for (int d = 0; d < HH; ++d) acc += row[d] * lin_w[d * HH + t];
  #pragma unroll
  for (int l = 0; l < LL; ++l) {
    float v = acc * wr_w[l * HH + t];
    for (int off = 32; off > 0; off >>= 1) v += __shfl_down(v, off, 64);
    if ((t & 63) == 0) part[l][t >> 6] = v;
  }
  __syncthreads();
  #pragma unroll
  for (int l = 0; l < LL; ++l) {
    float rd = part[l][0] + part[l][1] + wr_b[l];
    wrelp[(l * NRR + r) * HH + t] = rd * acc;
  }
}

// ---------------- beta0[l,b] ----------------
__global__ __launch_bounds__(256) void k_beta(
    const float* __restrict__ visit_node, const float* __restrict__ beta_w,
    const float* __restrict__ beta_b, float* __restrict__ beta0)
{
  int l = blockIdx.x >> 2, b = blockIdx.x & 3, t = threadIdx.x;
  __shared__ float red[256];
  float acc = 0.f;
  for (int n = t; n < NVV; n += 256)
    acc += visit_node[(b * VV + 0) * NVV + n] * beta_w[l * NVV + n];
  red[t] = acc;
  __syncthreads();
  for (int s = 128; s > 0; s >>= 1) {
    if (t < s) red[t] += red[t + s];
    __syncthreads();
  }
  if (t == 0) beta0[l * BB + b] = tanhf(red[0] + beta_b[l]) * expf(0.03f * 20.0f);
}

// ---------------- attn0[l,b,n] = softmax_v(vn*s+ab)[v=0]  (beta applied in anode) ----------------
__global__ __launch_bounds__(256) void k_attn(
    const float* __restrict__ visit_node, const float* __restrict__ snode,
    const float* __restrict__ alpha_b, float* __restrict__ attn0)
{
  int idx = blockIdx.x * 256 + threadIdx.x;
  if (idx >= BB * NVV) return;
  int b = idx / NVV, n = idx % NVV;
  float vn[VV];
  #pragma unroll
  for (int v = 0; v < VV; ++v) vn[v] = visit_node[(b * VV + v) * NVV + n];
  for (int l = 0; l < LL; ++l) {
    float s = (n < NN / BB) ? snode[l * NN + b * (NN / BB) + n] : 0.0f;
    float ab = alpha_b[l];
    float m = -1e30f;
    #pragma unroll
    for (int v = 0; v < VV; ++v) m = fmaxf(m, vn[v] * s + ab);
    float sum = 0.f;
    #pragma unroll
    for (int v = 0; v < VV; ++v) sum += expf(vn[v] * s + ab - m);
    attn0[(l * BB + b) * NVV + n] = expf(vn[0] * s + ab - m) / sum;
  }
}

// ---------------- anode[l,i] = attn0[l, batch[i], node_ids[i]] * beta0[l,batch[i]] ----------------
__global__ void k_anode(const int* __restrict__ node_ids, const int* __restrict__ batch,
                        const float* __restrict__ attn0, const float* __restrict__ beta0,
                        float* __restrict__ anode)
{
  int i = blockIdx.x * 256 + threadIdx.x;
  if (i >= NN) return;
  int b = batch[i], nid = node_ids[i];
  #pragma unroll
  for (int l = 0; l < LL; ++l)
    anode[l * NN + i] = attn0[(l * BB + b) * NVV + nid] * beta0[l * BB + b];
}

// ---------------- CSR build: histogram, scan, scatter ----------------
__global__ void k_hist(const int* __restrict__ edge_index, int* __restrict__ deg) {
  int e = blockIdx.x * 256 + threadIdx.x;
  if (e >= EE) return;
  atomicAdd(&deg[edge_index[EE + e]], 1);
}

__global__ __launch_bounds__(1024) void k_scan(const int* __restrict__ deg,
                                               int* __restrict__ row_ptr)
{
  int t = threadIdx.x;
  __shared__ int ps[1024];
  int local[8];
  int base = t * 8;
  int s = 0;
  #pragma unroll
  for (int j = 0; j < 8; ++j) {
    int idx = base + j;
    int v = (idx < NN) ? deg[idx] : 0;
    local[j] = s; s += v;
  }
  ps[t] = s;
  __syncthreads();
  for (int off = 1; off < 1024; off <<= 1) {
    int v = (t >= off) ? ps[t - off] : 0;
    __syncthreads();
    ps[t] += v;
    __syncthreads();
  }
  int excl = (t == 0) ? 0 : ps[t - 1];
  #pragma unroll
  for (int j = 0; j < 8; ++j) {
    int idx = base + j;
    if (idx < NN) row_ptr[idx] = excl + local[j];
  }
  if (t == 1023) row_ptr[NN] = ps[1023];
}

__global__ void k_scatter(const int* __restrict__ edge_index, const int* __restrict__ rel_ids,
                          const int* __restrict__ row_ptr, int* __restrict__ cursor,
                          int2* __restrict__ csr_sr, float* __restrict__ csr_a,
                          const float* __restrict__ anode)
{
  int e = blockIdx.x * 256 + threadIdx.x;
  if (e >= EE) return;
  int src = edge_index[e];
  int dst = edge_index[EE + e];
  int rid = rel_ids[e];
  int p = row_ptr[dst] + atomicAdd(&cursor[dst], 1);
  csr_sr[p] = make_int2(src, rid);
  csr_a[0 * EE + p] = anode[0 * NN + src];
  csr_a[1 * EE + p] = anode[1 * NN + src];
  csr_a[2 * EE + p] = anode[2 * NN + src];
}

// ---------------- fused gather + conv: 8 nodes/block, float4/lane, unroll-2 ----------------
__global__ __launch_bounds__(256) void k_gather_conv(
    const int* __restrict__ row_ptr, const int2* __restrict__ csr_sr,
    const float* __restrict__ csr_a, const float* __restrict__ xin,
    const float* __restrict__ wrelp, const float* __restrict__ conv_w,
    const float* __restrict__ conv_b, float* __restrict__ xout, int l)
{
  int t = threadIdx.x;
  int sub = t >> 5, lane = t & 31;
  int i = blockIdx.x * NPB + sub;
  __shared__ float aggrow[NPB][HH];
  const float4* __restrict__ xin4 = (const float4*)xin;
  const float4* __restrict__ wr4 = (const float4*)wrelp + (size_t)l * NRR * 32;
  const float4* __restrict__ cw4 = (const float4*)conv_w + (size_t)l * HH * 32;
  const float* __restrict__ ca = csr_a + (size_t)l * EE;

  float4 acc = xin4[i * 32 + lane];
  int k0 = row_ptr[i], k1 = row_ptr[i + 1];
  int k = k0;
  for (; k + 1 < k1; k += 2) {
    int2 sr0 = csr_sr[k];
    int2 sr1 = csr_sr[k + 1];
    float a0 = ca[k], a1 = ca[k + 1];
    float4 x0 = xin4[sr0.x * 32 + lane];
    float4 w0 = wr4[sr0.y * 32 + lane];
    float4 x1 = xin4[sr1.x * 32 + lane];
    float4 w1 = wr4[sr1.y * 32 + lane];
    acc.x += fmaxf(x0.x * a0 + w0.x, 0.f) + fmaxf(x1.x * a1 + w1.x, 0.f);
    acc.y += fmaxf(x0.y * a0 + w0.y, 0.f) + fmaxf(x1.y * a1 + w1.y, 0.f);
    acc.z += fmaxf(x0.z * a0 + w0.z, 0.f) + fmaxf(x1.z * a1 + w1.z, 0.f);
    acc.w += fmaxf(x0.w * a0 + w0.w, 0.f) + fmaxf(x1.w * a1 + w1.w, 0.f);
  }
  if (k < k1) {
    int2 sr0 = csr_sr[k];
    float a0 = ca[k];
    float4 x0 = xin4[sr0.x * 32 + lane];
    float4 w0 = wr4[sr0.y * 32 + lane];
    acc.x += fmaxf(x0.x * a0 + w0.x, 0.f);
    acc.y += fmaxf(x0.y * a0 + w0.y, 0.f);
    acc.z += fmaxf(x0.z * a0 + w0.z, 0.f);
    acc.w += fmaxf(x0.w * a0 + w0.w, 0.f);
  }
  *(float4*)&aggrow[sub][lane * 4] = acc;
  __syncthreads();

  float4 o = ((const float4*)conv_b)[l * 32 + lane];
  for (int d4 = 0; d4 < HH / 4; ++d4) {
    float4 ag = *(const float4*)&aggrow[sub][d4 * 4];
    float4 c0 = cw4[(d4 * 4 + 0) * 32 + lane];
    float4 c1 = cw4[(d4 * 4 + 1) * 32 + lane];
    float4 c2 = cw4[(d4 * 4 + 2) * 32 + lane];
    float4 c3 = cw4[(d4 * 4 + 3) * 32 + lane];
    o.x += ag.x * c0.x + ag.y * c1.x + ag.z * c2.x + ag.w * c3.x;
    o.y += ag.x * c0.y + ag.y * c1.y + ag.z * c2.y + ag.w * c3.y;
    o.z += ag.x * c0.z + ag.y * c1.z + ag.z * c2.z + ag.w * c3.z;
    o.w += ag.x * c0.w + ag.y * c1.w + ag.z * c2.w + ag.w * c3.w;
  }
  o.x = fmaxf(o.x, 0.f); o.y = fmaxf(o.y, 0.f);
  o.z = fmaxf(o.z, 0.f); o.w = fmaxf(o.w, 0.f);
  ((float4*)xout)[i * 32 + lane] = o;
}

// ---------------- x_graph partial sums (chunked, atomic) ----------------
__global__ __launch_bounds__(128) void k_xgraph(
    const float* __restrict__ x, float* __restrict__ xg_raw)
{
  int b = blockIdx.x >> 4, c = blockIdx.x & 15, t = threadIdx.x;
  const int per = (NN / BB) / 16;
  int base = b * (NN / BB) + c * per;
  float acc = 0.f;
  for (int i = 0; i < per; ++i) acc += x[(base + i) * HH + t];
  atomicAdd(&xg_raw[b * HH + t], acc);
}

// ---------------- x_node raw partial sums + denom ----------------
__global__ __launch_bounds__(128) void k_xnode(
    const float* __restrict__ ehr, const float* __restrict__ emb,
    float* __restrict__ xn_raw, float* __restrict__ denom)
{
  int b = blockIdx.x >> 5, c = blockIdx.x & 31, t = threadIdx.x;
  const int per = NVV / 32;
  int base = c * per;
  float acc = 0.f;
  for (int n = base; n < base + per; ++n)
    acc += ehr[b * NVV + n] * emb[n * HH + t];
  atomicAdd(&xn_raw[b * HH + t], acc);
  __shared__ float red[128];
  float dsum = 0.f;
  for (int n = base + t; n < base + per; n += 128) dsum += ehr[b * NVV + n];
  red[t] = dsum;
  __syncthreads();
  for (int s = 64; s > 0; s >>= 1) {
    if (t < s) red[t] += red[t + s];
    __syncthreads();
  }
  if (t == 0) atomicAdd(&denom[b], red[0]);
}

// ---------------- final: project x_node, concat, MLP ----------------
__global__ __launch_bounds__(128) void k_final(
    const float* __restrict__ xg_raw, const float* __restrict__ xn_raw,
    const float* __restrict__ denom, const float* __restrict__ lin_w,
    const float* __restrict__ lin_b, const float* __restrict__ mlp_w,
    const float* __restrict__ mlp_b, float* __restrict__ out)
{
  int b = blockIdx.x, t = threadIdx.x;
  __shared__ float xg[HH], xn[HH], xnp[HH];
  xg[t] = xg_raw[b * HH + t] * (1.0f / (NN / BB));
  xn[t] = xn_raw[b * HH + t] / denom[b];
  __syncthreads();
  float a3 = lin_b[t];
  #pragma unroll 4
  for (int d = 0; d < HH; ++d) a3 += xn[d] * lin_w[d * HH + t];
  xnp[t] = a3;
  __syncthreads();
  if (t < OO) {
    float a4 = mlp_b[t];
    #pragma unroll 4
    for (int h = 0; h < HH; ++h)
      a4 += xg[h] * mlp_w[h * OO + t] + xnp[h] * mlp_w[(HH + h) * OO + t];
    out[b * OO + t] = a4;
  }
}

extern "C" void kernel_launch(void* const* d_in, const int* in_sizes, int n_in,
                              void* d_out, int out_size, void* d_ws, size_t ws_size,
                              hipStream_t stream) {
  const int*   node_ids   = (const int*)d_in[0];
  const int*   rel_ids    = (const int*)d_in[1];
  const int*   edge_index = (const int*)d_in[2];
  const int*   batch      = (const int*)d_in[3];
  const float* visit_node = (const float*)d_in[4];
  const float* ehr        = (const float*)d_in[5];
  const float* node_emb   = (const float*)d_in[6];
  const float* rel_emb    = (const float*)d_in[7];
  const float* lin_w      = (const float*)d_in[8];
  const float* lin_b      = (const float*)d_in[9];
  const float* alpha_w    = (const float*)d_in[10];
  const float* alpha_b    = (const float*)d_in[11];
  const float* beta_w     = (const float*)d_in[12];
  const float* beta_b     = (const float*)d_in[13];
  const float* conv_w     = (const float*)d_in[14];
  const float* conv_b     = (const float*)d_in[15];
  const float* wr_w       = (const float*)d_in[16];
  const float* wr_b       = (const float*)d_in[17];
  const float* mlp_w      = (const float*)d_in[18];
  const float* mlp_b      = (const float*)d_in[19];
  float* out = (float*)d_out;

  float* ws = (float*)d_ws;
  float* xA     = ws; ws += NN * HH;
  float* xB     = ws; ws += NN * HH;
  float* wrelp  = ws; ws += LL * NRR * HH;
  float* snode  = ws; ws += LL * NN;
  float* beta0  = ws; ws += LL * BB;
  float* attn0  = ws; ws += LL * BB * NVV;
  float* anode  = ws; ws += LL * NN;
  float* xg_raw = ws; ws += BB * HH;   // xg_raw/xn_raw/denom contiguous (zeroed together)
  float* xn_raw = ws; ws += BB * HH;
  float* denom  = ws; ws += BB;
  int* iws      = (int*)ws;
  int* deg      = iws; iws += NN;      // deg/cursor contiguous (zeroed together)
  int* cursor   = iws; iws += NN;
  int* row_ptr  = iws; iws += NN + 2;  // +2 keeps following int2 array 8B-aligned
  int2* csr_sr  = (int2*)iws; iws += 2 * EE;
  float* csr_a  = (float*)iws;         // [LL][EE]

  int nf = BB * HH * 2 + BB;
  int ni = 2 * NN;
  hipLaunchKernelGGL(k_zero, dim3((ni + 255) / 256), dim3(256), 0, stream,
                     xg_raw, nf, deg, ni);

  hipLaunchKernelGGL(k_proj_nodes, dim3(NN / NPB), dim3(HH), 0, stream,
                     node_ids, node_emb, lin_w, lin_b, alpha_w, xA, snode);
  hipLaunchKernelGGL(k_proj_rels, dim3(NRR), dim3(HH), 0, stream,
                     rel_emb, lin_w, lin_b, wr_w, wr_b, wrelp);
  hipLaunchKernelGGL(k_beta, dim3(LL * BB), dim3(256), 0, stream,
                     visit_node, beta_w, beta_b, beta0);
  hipLaunchKernelGGL(k_attn, dim3((BB * NVV + 255) / 256), dim3(256), 0, stream,
                     visit_node, snode, alpha_b, attn0);
  hipLaunchKernelGGL(k_anode, dim3((NN + 255) / 256), dim3(256), 0, stream,
                     node_ids, batch, attn0, beta0, anode);

  hipLaunchKernelGGL(k_hist, dim3((EE + 255) / 256), dim3(256), 0, stream,
                     edge_index, deg);
  hipLaunchKernelGGL(k_scan, dim3(1), dim3(1024), 0, stream, deg, row_ptr);
  hipLaunchKernelGGL(k_scatter, dim3((EE + 255) / 256), dim3(256), 0, stream,
                     edge_index, rel_ids, row_ptr, cursor, csr_sr, csr_a, anode);

  const float* xin = xA;
  float* xout = xB;
  for (int l = 0; l < LL; ++l) {
    hipLaunchKernelGGL(k_gather_conv, dim3(NN / NPB), dim3(256), 0, stream,
                       row_ptr, csr_sr, csr_a, xin, wrelp, conv_w, conv_b, xout, l);
    const float* tmp = xin; xin = xout; xout = (float*)tmp;
  }
  // final x in xB (A->B, B->A, A->B)

  hipLaunchKernelGGL(k_xgraph, dim3(BB * 16), dim3(HH), 0, stream, xB, xg_raw);
  hipLaunchKernelGGL(k_xnode, dim3(BB * 32), dim3(HH), 0, stream,
                     ehr, node_emb, xn_raw, denom);
  hipLaunchKernelGGL(k_final, dim3(BB), dim3(HH), 0, stream,
                     xg_raw, xn_raw, denom, lin_w, lin_b, mlp_w, mlp_b, out);
}

// Round 14
// 311.309 us; speedup vs baseline: 4.1317x; 1.0302x over previous
//
#include <hip/hip_runtime.h>

#define NN  8000
#define EE  200000
#define BB  4
#define VV  20
#define NVV 8000
#define NRR 200
#define HH  128
#define OO  64
#define LL  3
#define NPB 8    // nodes per block (proj + gather)
#define NG  2000 // nodes per graph

// ---------------- node projection, 8 nodes/block + per-layer alpha dots ----------------
__global__ __launch_bounds__(128) void k_proj_nodes(
    const int* __restrict__ node_ids, const float* __restrict__ emb,
    const float* __restrict__ lin_w, const float* __restrict__ lin_b,
    const float* __restrict__ alpha_w, float* __restrict__ x,
    float* __restrict__ snode)
{
  int blk = blockIdx.x, t = threadIdx.x;
  __shared__ float er[NPB][HH];
  __shared__ float part[LL][NPB][2];
  int base = blk * NPB;
  #pragma unroll
  for (int n = 0; n < NPB; ++n)
    er[n][t] = emb[node_ids[base + n] * HH + t];
  __syncthreads();
  float bt = lin_b[t];
  float acc[NPB];
  #pragma unroll
  for (int n = 0; n < NPB; ++n) acc[n] = bt;
  for (int d4 = 0; d4 < HH / 4; ++d4) {
    float e4[NPB][4];
    #pragma unroll
    for (int n = 0; n < NPB; ++n) {
      float4 v = *(const float4*)&er[n][d4 * 4];
      e4[n][0] = v.x; e4[n][1] = v.y; e4[n][2] = v.z; e4[n][3] = v.w;
    }
    #pragma unroll
    for (int j = 0; j < 4; ++j) {
      float lwv = lin_w[(d4 * 4 + j) * HH + t];
      #pragma unroll
      for (int n = 0; n < NPB; ++n) acc[n] += e4[n][j] * lwv;
    }
  }
  #pragma unroll
  for (int n = 0; n < NPB; ++n) x[(base + n) * HH + t] = acc[n];
  #pragma unroll
  for (int l = 0; l < LL; ++l) {
    float aw = alpha_w[l * HH + t];
    #pragma unroll
    for (int n = 0; n < NPB; ++n) {
      float v = acc[n] * aw;
      for (int off = 32; off > 0; off >>= 1) v += __shfl_down(v, off, 64);
      if ((t & 63) == 0) part[l][n][t >> 6] = v;
    }
  }
  __syncthreads();
  if (t < LL * NPB) {
    int l = t / NPB, n = t % NPB;
    snode[l * NN + base + n] = part[l][n][0] + part[l][n][1];
  }
}

// ---------------- fused: relation projection (blocks 0..199) + beta (200..211) + zeroing ----------------
__global__ __launch_bounds__(128) void k_prb(
    const float* __restrict__ rel_emb, const float* __restrict__ lin_w,
    const float* __restrict__ lin_b, const float* __restrict__ wr_w,
    const float* __restrict__ wr_b, const float* __restrict__ visit_node,
    const float* __restrict__ beta_w, const float* __restrict__ beta_b,
    float* __restrict__ wrelp, float* __restrict__ beta0,
    int* __restrict__ iz, float* __restrict__ fz)
{
  int blk = blockIdx.x, t = threadIdx.x;
  int idx = blk * 128 + t;
  if (idx < 2 * NN) iz[idx] = 0;                 // deg + cursor
  if (idx < BB * HH * 2 + BB) fz[idx] = 0.f;     // xg_raw + xn_raw + denom
  if (blk < NRR) {
    __shared__ float row[HH];
    __shared__ float part[LL][2];
    row[t] = rel_emb[blk * HH + t];
    __syncthreads();
    float acc = lin_b[t];
    #pragma unroll 4
    for (int d = 0; d < HH; ++d) acc += row[d] * lin_w[d * HH + t];
    #pragma unroll
    for (int l = 0; l < LL; ++l) {
      float v = acc * wr_w[l * HH + t];
      for (int off = 32; off > 0; off >>= 1) v += __shfl_down(v, off, 64);
      if ((t & 63) == 0) part[l][t >> 6] = v;
    }
    __syncthreads();
    #pragma unroll
    for (int l = 0; l < LL; ++l) {
      float rd = part[l][0] + part[l][1] + wr_b[l];
      wrelp[(l * NRR + blk) * HH + t] = rd * acc;
    }
  } else {
    int j = blk - NRR;          // 0..11
    int l = j >> 2, b = j & 3;
    float acc = 0.f;
    for (int n = t; n < NVV; n += 128)
      acc += visit_node[(b * VV + 0) * NVV + n] * beta_w[l * NVV + n];
    for (int off = 32; off > 0; off >>= 1) acc += __shfl_down(acc, off, 64);
    __shared__ float bred[2];
    if ((t & 63) == 0) bred[t >> 6] = acc;
    __syncthreads();
    if (t == 0)
      beta0[l * BB + b] = tanhf(bred[0] + bred[1] + beta_b[l]) * expf(0.03f * 20.0f);
  }
}

// ---------------- fused: per-node attention (softmax col @ node) + degree histogram ----------------
__global__ __launch_bounds__(256) void k_anode_hist(
    const int* __restrict__ node_ids, const int* __restrict__ batch,
    const int* __restrict__ edge_index, const float* __restrict__ visit_node,
    const float* __restrict__ snode, const float* __restrict__ alpha_b,
    const float* __restrict__ beta0, float* __restrict__ anode,
    int* __restrict__ deg)
{
  int idx = blockIdx.x * 256 + threadIdx.x;
  if (idx < EE) atomicAdd(&deg[edge_index[EE + idx]], 1);
  if (idx >= NN) return;
  int b = batch[idx], nid = node_ids[idx];
  float vn[VV];
  #pragma unroll
  for (int v = 0; v < VV; ++v) vn[v] = visit_node[(b * VV + v) * NVV + nid];
  #pragma unroll
  for (int l = 0; l < LL; ++l) {
    float s = (nid < NG) ? snode[l * NN + b * NG + nid] : 0.0f;
    float ab = alpha_b[l];
    float m = -1e30f;
    #pragma unroll
    for (int v = 0; v < VV; ++v) m = fmaxf(m, vn[v] * s + ab);
    float sum = 0.f;
    #pragma unroll
    for (int v = 0; v < VV; ++v) sum += expf(vn[v] * s + ab - m);
    anode[l * NN + idx] = (expf(vn[0] * s + ab - m) / sum) * beta0[l * BB + b];
  }
}

// ---------------- scan (row_ptr) ----------------
__global__ __launch_bounds__(1024) void k_scan(const int* __restrict__ deg,
                                               int* __restrict__ row_ptr)
{
  int t = threadIdx.x;
  __shared__ int ps[1024];
  int local[8];
  int base = t * 8;
  int s = 0;
  #pragma unroll
  for (int j = 0; j < 8; ++j) {
    int idx = base + j;
    int v = (idx < NN) ? deg[idx] : 0;
    local[j] = s; s += v;
  }
  ps[t] = s;
  __syncthreads();
  for (int off = 1; off < 1024; off <<= 1) {
    int v = (t >= off) ? ps[t - off] : 0;
    __syncthreads();
    ps[t] += v;
    __syncthreads();
  }
  int excl = (t == 0) ? 0 : ps[t - 1];
  #pragma unroll
  for (int j = 0; j < 8; ++j) {
    int idx = base + j;
    if (idx < NN) row_ptr[idx] = excl + local[j];
  }
  if (t == 1023) row_ptr[NN] = ps[1023];
}

// ---------------- scatter: CSR (src, rid) only ----------------
__global__ void k_scatter(const int* __restrict__ edge_index, const int* __restrict__ rel_ids,
                          const int* __restrict__ row_ptr, int* __restrict__ cursor,
                          int2* __restrict__ csr_sr)
{
  int e = blockIdx.x * 256 + threadIdx.x;
  if (e >= EE) return;
  int dst = edge_index[EE + e];
  int p = row_ptr[dst] + atomicAdd(&cursor[dst], 1);
  csr_sr[p] = make_int2(edge_index[e], rel_ids[e]);
}

// ---------------- fused gather + conv: 8 nodes/block, float4/lane, unroll-4 ----------------
__global__ __launch_bounds__(256) void k_gather_conv(
    const int* __restrict__ row_ptr, const int2* __restrict__ csr_sr,
    const float* __restrict__ anode, const float* __restrict__ xin,
    const float* __restrict__ wrelp, const float* __restrict__ conv_w,
    const float* __restrict__ conv_b, float* __restrict__ xout, int l)
{
  int t = threadIdx.x;
  int sub = t >> 5, lane = t & 31;
  int i = blockIdx.x * NPB + sub;
  __shared__ float aggrow[NPB][HH];
  const float4* __restrict__ xin4 = (const float4*)xin;
  const float4* __restrict__ wr4 = (const float4*)wrelp + (size_t)l * NRR * 32;
  const float4* __restrict__ cw4 = (const float4*)conv_w + (size_t)l * HH * 32;
  const float* __restrict__ an = anode + (size_t)l * NN;

  float4 acc = xin4[i * 32 + lane];
  int k0 = row_ptr[i], k1 = row_ptr[i + 1];
  int k = k0;
  for (; k + 3 < k1; k += 4) {
    int2 s0 = csr_sr[k],     s1 = csr_sr[k + 1];
    int2 s2 = csr_sr[k + 2], s3 = csr_sr[k + 3];
    float a0 = an[s0.x], a1 = an[s1.x], a2 = an[s2.x], a3 = an[s3.x];
    float4 x0 = xin4[s0.x * 32 + lane], w0 = wr4[s0.y * 32 + lane];
    float4 x1 = xin4[s1.x * 32 + lane], w1 = wr4[s1.y * 32 + lane];
    float4 x2 = xin4[s2.x * 32 + lane], w2 = wr4[s2.y * 32 + lane];
    float4 x3 = xin4[s3.x * 32 + lane], w3 = wr4[s3.y * 32 + lane];
    acc.x += fmaxf(x0.x * a0 + w0.x, 0.f) + fmaxf(x1.x * a1 + w1.x, 0.f)
           + fmaxf(x2.x * a2 + w2.x, 0.f) + fmaxf(x3.x * a3 + w3.x, 0.f);
    acc.y += fmaxf(x0.y * a0 + w0.y, 0.f) + fmaxf(x1.y * a1 + w1.y, 0.f)
           + fmaxf(x2.y * a2 + w2.y, 0.f) + fmaxf(x3.y * a3 + w3.y, 0.f);
    acc.z += fmaxf(x0.z * a0 + w0.z, 0.f) + fmaxf(x1.z * a1 + w1.z, 0.f)
           + fmaxf(x2.z * a2 + w2.z, 0.f) + fmaxf(x3.z * a3 + w3.z, 0.f);
    acc.w += fmaxf(x0.w * a0 + w0.w, 0.f) + fmaxf(x1.w * a1 + w1.w, 0.f)
           + fmaxf(x2.w * a2 + w2.w, 0.f) + fmaxf(x3.w * a3 + w3.w, 0.f);
  }
  for (; k < k1; ++k) {
    int2 s0 = csr_sr[k];
    float a0 = an[s0.x];
    float4 x0 = xin4[s0.x * 32 + lane], w0 = wr4[s0.y * 32 + lane];
    acc.x += fmaxf(x0.x * a0 + w0.x, 0.f);
    acc.y += fmaxf(x0.y * a0 + w0.y, 0.f);
    acc.z += fmaxf(x0.z * a0 + w0.z, 0.f);
    acc.w += fmaxf(x0.w * a0 + w0.w, 0.f);
  }
  *(float4*)&aggrow[sub][lane * 4] = acc;
  __syncthreads();

  float4 o = ((const float4*)conv_b)[l * 32 + lane];
  for (int d4 = 0; d4 < HH / 4; ++d4) {
    float4 ag = *(const float4*)&aggrow[sub][d4 * 4];
    float4 c0 = cw4[(d4 * 4 + 0) * 32 + lane];
    float4 c1 = cw4[(d4 * 4 + 1) * 32 + lane];
    float4 c2 = cw4[(d4 * 4 + 2) * 32 + lane];
    float4 c3 = cw4[(d4 * 4 + 3) * 32 + lane];
    o.x += ag.x * c0.x + ag.y * c1.x + ag.z * c2.x + ag.w * c3.x;
    o.y += ag.x * c0.y + ag.y * c1.y + ag.z * c2.y + ag.w * c3.y;
    o.z += ag.x * c0.z + ag.y * c1.z + ag.z * c2.z + ag.w * c3.z;
    o.w += ag.x * c0.w + ag.y * c1.w + ag.z * c2.w + ag.w * c3.w;
  }
  o.x = fmaxf(o.x, 0.f); o.y = fmaxf(o.y, 0.f);
  o.z = fmaxf(o.z, 0.f); o.w = fmaxf(o.w, 0.f);
  ((float4*)xout)[i * 32 + lane] = o;
}

// ---------------- fused pooling: x_graph (blocks 0..63) + x_node (64..191) ----------------
__global__ __launch_bounds__(128) void k_pool(
    const float* __restrict__ x, const float* __restrict__ ehr,
    const float* __restrict__ emb, float* __restrict__ xg_raw,
    float* __restrict__ xn_raw, float* __restrict__ denom)
{
  int t = threadIdx.x;
  if (blockIdx.x < 64) {
    int b = blockIdx.x >> 4, c = blockIdx.x & 15;
    const int per = NG / 16;
    int base = b * NG + c * per;
    float acc = 0.f;
    for (int i = 0; i < per; ++i) acc += x[(base + i) * HH + t];
    atomicAdd(&xg_raw[b * HH + t], acc);
  } else {
    int ib = blockIdx.x - 64;
    int b = ib >> 5, c = ib & 31;
    const int per = NVV / 32;
    int base = c * per;
    float acc = 0.f;
    for (int n = base; n < base + per; ++n)
      acc += ehr[b * NVV + n] * emb[n * HH + t];
    atomicAdd(&xn_raw[b * HH + t], acc);
    __shared__ float red[128];
    float dsum = 0.f;
    for (int n = base + t; n < base + per; n += 128) dsum += ehr[b * NVV + n];
    red[t] = dsum;
    __syncthreads();
    for (int s = 64; s > 0; s >>= 1) {
      if (t < s) red[t] += red[t + s];
      __syncthreads();
    }
    if (t == 0) atomicAdd(&denom[b], red[0]);
  }
}

// ---------------- final: project x_node, concat, MLP ----------------
__global__ __launch_bounds__(128) void k_final(
    const float* __restrict__ xg_raw, const float* __restrict__ xn_raw,
    const float* __restrict__ denom, const float* __restrict__ lin_w,
    const float* __restrict__ lin_b, const float* __restrict__ mlp_w,
    const float* __restrict__ mlp_b, float* __restrict__ out)
{
  int b = blockIdx.x, t = threadIdx.x;
  __shared__ float xg[HH], xn[HH], xnp[HH];
  xg[t] = xg_raw[b * HH + t] * (1.0f / NG);
  xn[t] = xn_raw[b * HH + t] / denom[b];
  __syncthreads();
  float a3 = lin_b[t];
  #pragma unroll 4
  for (int d = 0; d < HH; ++d) a3 += xn[d] * lin_w[d * HH + t];
  xnp[t] = a3;
  __syncthreads();
  if (t < OO) {
    float a4 = mlp_b[t];
    #pragma unroll 4
    for (int h = 0; h < HH; ++h)
      a4 += xg[h] * mlp_w[h * OO + t] + xnp[h] * mlp_w[(HH + h) * OO + t];
    out[b * OO + t] = a4;
  }
}

extern "C" void kernel_launch(void* const* d_in, const int* in_sizes, int n_in,
                              void* d_out, int out_size, void* d_ws, size_t ws_size,
                              hipStream_t stream) {
  const int*   node_ids   = (const int*)d_in[0];
  const int*   rel_ids    = (const int*)d_in[1];
  const int*   edge_index = (const int*)d_in[2];
  const int*   batch      = (const int*)d_in[3];
  const float* visit_node = (const float*)d_in[4];
  const float* ehr        = (const float*)d_in[5];
  const float* node_emb   = (const float*)d_in[6];
  const float* rel_emb    = (const float*)d_in[7];
  const float* lin_w      = (const float*)d_in[8];
  const float* lin_b      = (const float*)d_in[9];
  const float* alpha_w    = (const float*)d_in[10];
  const float* alpha_b    = (const float*)d_in[11];
  const float* beta_w     = (const float*)d_in[12];
  const float* beta_b     = (const float*)d_in[13];
  const float* conv_w     = (const float*)d_in[14];
  const float* conv_b     = (const float*)d_in[15];
  const float* wr_w       = (const float*)d_in[16];
  const float* wr_b       = (const float*)d_in[17];
  const float* mlp_w      = (const float*)d_in[18];
  const float* mlp_b      = (const float*)d_in[19];
  float* out = (float*)d_out;

  float* ws = (float*)d_ws;
  float* xA     = ws; ws += NN * HH;
  float* xB     = ws; ws += NN * HH;
  float* wrelp  = ws; ws += LL * NRR * HH;
  float* snode  = ws; ws += LL * NN;
  float* beta0  = ws; ws += LL * BB;
  float* anode  = ws; ws += LL * NN;
  float* xg_raw = ws; ws += BB * HH;   // xg_raw/xn_raw/denom contiguous (zeroed together)
  float* xn_raw = ws; ws += BB * HH;
  float* denom  = ws; ws += BB;
  int* iws      = (int*)ws;
  int* deg      = iws; iws += NN;      // deg/cursor contiguous (zeroed together)
  int* cursor   = iws; iws += NN;
  int* row_ptr  = iws; iws += NN + 2;  // +2 pad -> csr_sr stays 8B-aligned
  int2* csr_sr  = (int2*)iws;

  // 1: node projection + snode
  hipLaunchKernelGGL(k_proj_nodes, dim3(NN / NPB), dim3(HH), 0, stream,
                     node_ids, node_emb, lin_w, lin_b, alpha_w, xA, snode);
  // 2: rel projection + beta + zero(deg,cursor,accum)
  hipLaunchKernelGGL(k_prb, dim3(NRR + LL * BB), dim3(HH), 0, stream,
                     rel_emb, lin_w, lin_b, wr_w, wr_b, visit_node, beta_w,
                     beta_b, wrelp, beta0, deg, xg_raw);
  // 3: per-node attention + degree histogram
  hipLaunchKernelGGL(k_anode_hist, dim3((EE + 255) / 256), dim3(256), 0, stream,
                     node_ids, batch, edge_index, visit_node, snode, alpha_b,
                     beta0, anode, deg);
  // 4: scan
  hipLaunchKernelGGL(k_scan, dim3(1), dim3(1024), 0, stream, deg, row_ptr);
  // 5: scatter
  hipLaunchKernelGGL(k_scatter, dim3((EE + 255) / 256), dim3(256), 0, stream,
                     edge_index, rel_ids, row_ptr, cursor, csr_sr);
  // 6-8: layers
  const float* xin = xA;
  float* xout = xB;
  for (int l = 0; l < LL; ++l) {
    hipLaunchKernelGGL(k_gather_conv, dim3(NN / NPB), dim3(256), 0, stream,
                       row_ptr, csr_sr, anode, xin, wrelp, conv_w, conv_b, xout, l);
    const float* tmp = xin; xin = xout; xout = (float*)tmp;
  }
  // final x in xB (A->B, B->A, A->B)
  // 9: pooling (x_graph + x_node partials)
  hipLaunchKernelGGL(k_pool, dim3(64 + 128), dim3(HH), 0, stream,
                     xB, ehr, node_emb, xg_raw, xn_raw, denom);
  // 10: head
  hipLaunchKernelGGL(k_final, dim3(BB), dim3(HH), 0, stream,
                     xg_raw, xn_raw, denom, lin_w, lin_b, mlp_w, mlp_b, out);
}